// Round 5
// baseline (171.262 us; speedup 1.0000x reference)
//
#include <hip/hip_runtime.h>
#include <math.h>

// Geodesic loss: mean over B of acos(clip((sum_ij m1*m2 - 1)*0.5, -1, 1)).
//
// R9. History: three structurally disjoint kernels (LDS+barriers / pure-reg
// uncoalesced / wave-private-LDS no-barriers) ALL pin at 56-58us with every
// counter idle (VALUBusy<5%, HBM<=22%, conflicts 0). Uncoalesced R7 got MORE
// HBM BW (1.73 vs 1.33 TB/s) than coalesced variants -> neither coalescing
// nor request rate is the limiter. Remaining shared structure: per-wave
// 18-load bursts with one wait-all (single long latency exposure per tile)
// and <=50% occupancy. R9 tests the last untested regime -- m13-copy style:
// fine-grained paced loads, zero LDS in the hot loop, 32 waves/CU.
//
// Lane-quad decomposition: lanes 4t..4t+3 own a 4-matrix group (36 floats =
// 9 float4). Lane q loads float4 9Q+q and 9Q+4+q (4 consecutive lanes =
// contiguous 64B line, fully used) + the shared tail float4 9Q+8. Per-matrix
// partials built branchlessly from prefix sums; two __shfl_xor (1,2) =
// quad_perm DPP finish all four 9-float dots. No LDS, no barriers, ~50 VGPR
// -> 8 waves/SIMD. Each lane finishes one matrix per iteration (acos+accum).

#define TPB 256
#define NBLOCKS 2048

__global__ __launch_bounds__(TPB) void geo_kernel(
    const float* __restrict__ a, const float* __restrict__ b,
    float* __restrict__ out, float invM, int M)
{
    __shared__ float wsum[TPB / 64];
    const int tid = threadIdx.x;
    const int q   = tid & 3;                    // position within lane-quad

    float sum = 0.0f;

    const long long G    = (long long)M >> 2;   // 4-matrix groups
    const long long Q0   = (long long)blockIdx.x * (TPB / 4) + (tid >> 2);
    const long long Qstr = (long long)gridDim.x * (TPB / 4);

    const float4* __restrict__ a4 = (const float4*)a;
    const float4* __restrict__ b4 = (const float4*)b;

    for (long long Q = Q0; Q < G; Q += Qstr) {
        const float4* __restrict__ pa = a4 + 9 * Q;
        const float4* __restrict__ pb = b4 + 9 * Q;
        // coalesced: lanes 4t..4t+3 hit one contiguous 64B line per instr
        const float4 A0 = pa[q], A1 = pa[4 + q], A2 = pa[8];
        const float4 B0 = pb[q], B1 = pb[4 + q], B2 = pb[8];

        float4 t0, t1;
        t0.x = A0.x * B0.x; t0.y = A0.y * B0.y;
        t0.z = A0.z * B0.z; t0.w = A0.w * B0.w;
        t1.x = A1.x * B1.x; t1.y = A1.y * B1.y;
        t1.z = A1.z * B1.z; t1.w = A1.w * B1.w;

        // prefix pieces
        const float c01 = t0.x + t0.y;
        const float T0  = (c01 + t0.z) + t0.w;
        const float d01 = t1.x + t1.y;
        const float T1  = (d01 + t1.z) + t1.w;

        // per-matrix partials: float slot 4q+c (t0) / 16+4q+c (t1) belongs
        // to matrix slot/9 of the group. Branchless per-lane selection.
        float P0 = (q == 3) ? 0.0f : ((q == 2) ? t0.x : T0);
        float P1 = (q == 0) ? d01  : ((q == 1) ? 0.0f
                   : ((q == 2) ? (T0 - t0.x) : T0));
        float P2 = (q == 0) ? (T1 - d01) : ((q == 1) ? T1
                   : ((q == 2) ? (T1 - t1.w) : 0.0f));
        float P3 = (q == 2) ? t1.w : ((q == 3) ? T1 : 0.0f);

        // quad all-reduce: xor-1 + xor-2 (DPP quad_perm, no LDS)
        P0 += __shfl_xor(P0, 1, 64); P0 += __shfl_xor(P0, 2, 64);
        P1 += __shfl_xor(P1, 1, 64); P1 += __shfl_xor(P1, 2, 64);
        P2 += __shfl_xor(P2, 1, 64); P2 += __shfl_xor(P2, 2, 64);
        P3 += __shfl_xor(P3, 1, 64); P3 += __shfl_xor(P3, 2, 64);

        // shared tail float4 (floats 32..35, matrix 3) -- counted once, on
        // the lane that owns matrix 3
        const float u0 = A2.x * B2.x, u1 = A2.y * B2.y;
        const float u2 = A2.z * B2.z, u3 = A2.w * B2.w;
        const float dl2 = (u0 + u1) + (u2 + u3);

        const float d = (q == 0) ? P0 : (q == 1) ? P1
                      : (q == 2) ? P2 : (P3 + dl2);
        const float cv = fminf(1.0f, fmaxf(-1.0f, (d - 1.0f) * 0.5f));
        sum += acosf(cv);
    }

    // tail matrices beyond 4*G (empty when M % 4 == 0)
    {
        const long long gid    = (long long)blockIdx.x * TPB + tid;
        const long long stride = (long long)gridDim.x * TPB;
        for (long long m = 4 * G + gid; m < M; m += stride) {
            float d = 0.0f;
            #pragma unroll
            for (int j = 0; j < 9; ++j)
                d = fmaf(a[m * 9 + j], b[m * 9 + j], d);
            sum += acosf(fminf(1.0f, fmaxf(-1.0f, (d - 1.0f) * 0.5f)));
        }
    }

    // wave shuffle reduce -> per-block LDS reduce -> one atomic per block
    #pragma unroll
    for (int off = 32; off > 0; off >>= 1)
        sum += __shfl_down(sum, off, 64);
    if ((tid & 63) == 0) wsum[tid >> 6] = sum;
    __syncthreads();
    if (tid == 0) {
        float s = 0.0f;
        #pragma unroll
        for (int i = 0; i < TPB / 64; ++i) s += wsum[i];
        atomicAdd(out, s * invM);   // device-scope by default
    }
}

extern "C" void kernel_launch(void* const* d_in, const int* in_sizes, int n_in,
                              void* d_out, int out_size, void* d_ws, size_t ws_size,
                              hipStream_t stream) {
    const float* a = (const float*)d_in[0];
    const float* b = (const float*)d_in[1];
    float* out = (float*)d_out;

    const int n = in_sizes[0];   // flat float count = 9*M
    const int M = n / 9;         // number of 3x3 matrices

    // d_out is re-poisoned 0xAA before every timed launch; zero it (async,
    // graph-capture safe), then accumulate the mean with per-block atomics.
    hipMemsetAsync(out, 0, (size_t)out_size * sizeof(float), stream);
    geo_kernel<<<NBLOCKS, TPB, 0, stream>>>(a, b, out, 1.0f / (float)M, M);
}

// Round 6
// 162.655 us; speedup vs baseline: 1.0529x; 1.0529x over previous
//
#include <hip/hip_runtime.h>
#include <math.h>

// Geodesic loss: mean over B of acos(clip((sum_ij m1*m2 - 1)*0.5, -1, 1)).
//
// R10 theory. Four disjoint structures (R2/R7/R8/R9) all pin at 56-58us,
// all CU pipes idle. Decisive counter pattern: FETCH_SIZE ~= 78MB ~= ONE
// input array on EVERY dispatch of EVERY kernel, and 75.5MB/57.6us =
// 1.31 TB/s = measured hbm_gbps exactly. Kernel time == miss-stream time
// at 1/5 of the 6.29 TB/s verified streaming ceiling, while the other
// array is LLC-served. Hypothesis: the mixed hit/miss LLC path (misses
// allocate into LLC, fill/victim path throttles) caps miss service; no
// CU-side structure change can affect it. Fix: NON-TEMPORAL loads (nt, no
// LLC allocate) -> pure HBM stream, the exact regime m13 measured 6.29
// TB/s in. Also: kill the 2048-to-one-address atomicAdd tail (serialized
// at one LLC bank) -- partials to d_ws, tiny second kernel reduces; drops
// the memset dispatch too. Quad math kept bit-identical to verified R9;
// added pure-register next-iteration prefetch (no barriers anywhere, so
// nothing drains it).

typedef float f4 __attribute__((ext_vector_type(4)));

#define TPB 256
#define NBLOCKS 2048

#define LOADQ(P, pa, pb)                                                    \
    P##A0 = __builtin_nontemporal_load((pa) + q);                           \
    P##A1 = __builtin_nontemporal_load((pa) + 4 + q);                       \
    P##A2 = __builtin_nontemporal_load((pa) + 8);                           \
    P##B0 = __builtin_nontemporal_load((pb) + q);                           \
    P##B1 = __builtin_nontemporal_load((pb) + 4 + q);                       \
    P##B2 = __builtin_nontemporal_load((pb) + 8);

__global__ __launch_bounds__(TPB) void geo_partial(
    const float* __restrict__ a, const float* __restrict__ b,
    float* __restrict__ ws, float* __restrict__ out, float invM, int M,
    int use_atomic)
{
    __shared__ float wsum[TPB / 64];
    const int tid = threadIdx.x;
    const int q   = tid & 3;                    // position within lane-quad

    float sum = 0.0f;

    const long long G    = (long long)M >> 2;   // 4-matrix groups
    const long long Q0   = (long long)blockIdx.x * (TPB / 4) + (tid >> 2);
    const long long Qstr = (long long)gridDim.x * (TPB / 4);

    const f4* __restrict__ a4 = (const f4*)a;
    const f4* __restrict__ b4 = (const f4*)b;

    f4 A0, A1, A2, B0, B1, B2;
    long long Q = Q0;
    if (Q < G) {
        const f4* pa = a4 + 9 * Q;
        const f4* pb = b4 + 9 * Q;
        LOADQ(, pa, pb)
    }

    while (Q < G) {
        const long long Qn = Q + Qstr;
        // register prefetch of next iteration: in flight across this
        // iteration's compute; nothing (no barrier) ever drains it early
        f4 NA0, NA1, NA2, NB0, NB1, NB2;
        if (Qn < G) {
            const f4* pa = a4 + 9 * Qn;
            const f4* pb = b4 + 9 * Qn;
            LOADQ(N, pa, pb)
        }

        // ---- R9-verified quad math (bit-identical) ----
        f4 t0, t1;
        t0.x = A0.x * B0.x; t0.y = A0.y * B0.y;
        t0.z = A0.z * B0.z; t0.w = A0.w * B0.w;
        t1.x = A1.x * B1.x; t1.y = A1.y * B1.y;
        t1.z = A1.z * B1.z; t1.w = A1.w * B1.w;

        const float c01 = t0.x + t0.y;
        const float T0  = (c01 + t0.z) + t0.w;
        const float d01 = t1.x + t1.y;
        const float T1  = (d01 + t1.z) + t1.w;

        float P0 = (q == 3) ? 0.0f : ((q == 2) ? t0.x : T0);
        float P1 = (q == 0) ? d01  : ((q == 1) ? 0.0f
                   : ((q == 2) ? (T0 - t0.x) : T0));
        float P2 = (q == 0) ? (T1 - d01) : ((q == 1) ? T1
                   : ((q == 2) ? (T1 - t1.w) : 0.0f));
        float P3 = (q == 2) ? t1.w : ((q == 3) ? T1 : 0.0f);

        P0 += __shfl_xor(P0, 1, 64); P0 += __shfl_xor(P0, 2, 64);
        P1 += __shfl_xor(P1, 1, 64); P1 += __shfl_xor(P1, 2, 64);
        P2 += __shfl_xor(P2, 1, 64); P2 += __shfl_xor(P2, 2, 64);
        P3 += __shfl_xor(P3, 1, 64); P3 += __shfl_xor(P3, 2, 64);

        const float u0 = A2.x * B2.x, u1 = A2.y * B2.y;
        const float u2 = A2.z * B2.z, u3 = A2.w * B2.w;
        const float dl2 = (u0 + u1) + (u2 + u3);

        const float d = (q == 0) ? P0 : (q == 1) ? P1
                      : (q == 2) ? P2 : (P3 + dl2);
        const float cv = fminf(1.0f, fmaxf(-1.0f, (d - 1.0f) * 0.5f));
        sum += acosf(cv);
        // ---- end quad math ----

        if (Qn < G) {
            A0 = NA0; A1 = NA1; A2 = NA2;
            B0 = NB0; B1 = NB1; B2 = NB2;
        }
        Q = Qn;
    }

    // tail matrices beyond 4*G (empty when M % 4 == 0)
    {
        const long long gid    = (long long)blockIdx.x * TPB + tid;
        const long long stride = (long long)gridDim.x * TPB;
        for (long long m = 4 * G + gid; m < M; m += stride) {
            float dd = 0.0f;
            #pragma unroll
            for (int j = 0; j < 9; ++j)
                dd = fmaf(a[m * 9 + j], b[m * 9 + j], dd);
            sum += acosf(fminf(1.0f, fmaxf(-1.0f, (dd - 1.0f) * 0.5f)));
        }
    }

    // wave shuffle reduce -> per-block LDS reduce
    #pragma unroll
    for (int off = 32; off > 0; off >>= 1)
        sum += __shfl_down(sum, off, 64);
    if ((tid & 63) == 0) wsum[tid >> 6] = sum;
    __syncthreads();
    if (tid == 0) {
        float s = 0.0f;
        #pragma unroll
        for (int i = 0; i < TPB / 64; ++i) s += wsum[i];
        if (use_atomic) atomicAdd(out, s * invM);   // fallback path
        else            ws[blockIdx.x] = s;          // no contention
    }
}

__global__ __launch_bounds__(256) void geo_finish(
    const float* __restrict__ ws, float* __restrict__ out,
    float invM, int nb)
{
    __shared__ float wsum[4];
    float s = 0.0f;
    for (int i = threadIdx.x; i < nb; i += 256) s += ws[i];
    #pragma unroll
    for (int off = 32; off > 0; off >>= 1)
        s += __shfl_down(s, off, 64);
    if ((threadIdx.x & 63) == 0) wsum[threadIdx.x >> 6] = s;
    __syncthreads();
    if (threadIdx.x == 0)
        out[0] = (wsum[0] + wsum[1] + wsum[2] + wsum[3]) * invM;
}

extern "C" void kernel_launch(void* const* d_in, const int* in_sizes, int n_in,
                              void* d_out, int out_size, void* d_ws, size_t ws_size,
                              hipStream_t stream) {
    const float* a = (const float*)d_in[0];
    const float* b = (const float*)d_in[1];
    float* out = (float*)d_out;

    const int n = in_sizes[0];   // flat float count = 9*M
    const int M = n / 9;         // number of 3x3 matrices

    const bool ws_ok = (ws_size >= (size_t)NBLOCKS * sizeof(float));
    if (!ws_ok) {
        // atomic fallback needs a zeroed accumulator (d_out is poisoned)
        hipMemsetAsync(out, 0, (size_t)out_size * sizeof(float), stream);
    }
    geo_partial<<<NBLOCKS, TPB, 0, stream>>>(
        a, b, (float*)d_ws, out, 1.0f / (float)M, M, ws_ok ? 0 : 1);
    if (ws_ok) {
        geo_finish<<<1, 256, 0, stream>>>(
            (const float*)d_ws, out, 1.0f / (float)M, NBLOCKS);
    }
}

// Round 7
// 157.610 us; speedup vs baseline: 1.0866x; 1.0320x over previous
//
#include <hip/hip_runtime.h>
#include <math.h>

// Geodesic loss: mean over B of acos(clip((sum_ij m1*m2 - 1)*0.5, -1, 1)).
//
// R11. R10's nt loads broke the 57us floor: geo_partial left the top-5
// (all fills at 44.5-44.7us now) -> kernel ~44us, 3.4 TB/s. The harness's
// own 302MB poison fills run at 6.77 TB/s in the same timed loop, so the
// memory system has 2x headroom. Remaining-gap theory: R9/R10 quad chunks
// sit at 144*Q mod 64 = {0,16,32,48} -> 3/4 of 64B quad-loads straddle two
// lines; with the 2 broadcast tail loads that's ~9 line-requests per 4.5
// lines of data = 2.0x request amplification at TA/TCC == exactly the
// 3.4-vs-6.8 gap. Fix: ALIGNED tiling. Each quad owns 16 matrices = 576B
// per input (64-multiple): lane q nt-loads f4[36*gq + 4k + q], k=0..8 --
// every quad-chunk is ONE aligned 64B line, 1KB/instr, zero straddle, zero
// broadcast. Reassembly in-register: per 9-float4 window (float4-aligned),
// route each float4 via prefix sums + selects on r=4k+q-9g into 4 matrix
// partials (splits at r=2,4,6), quad-all-reduce with shfl_xor(1,2); lane q
// takes matrix 4g+q. Routing table hand-verified for all (q,k,g).

typedef float f4 __attribute__((ext_vector_type(4)));

#define TPB 256
#define NBLOCKS 2048

__global__ __launch_bounds__(TPB) void geo_partial(
    const float* __restrict__ a, const float* __restrict__ b,
    float* __restrict__ ws, float* __restrict__ out, float invM, int M,
    int use_atomic)
{
    __shared__ float wsum[TPB / 64];
    const int tid = threadIdx.x;
    const int q   = tid & 3;                    // lane position within quad

    float sum = 0.0f;

    const long long NQ   = (long long)M >> 4;   // 16-matrix superblocks
    const long long gq0  = (long long)blockIdx.x * (TPB / 4) + (tid >> 2);
    const long long qstr = (long long)gridDim.x * (TPB / 4);

    const f4* __restrict__ a4 = (const f4*)a;
    const f4* __restrict__ b4 = (const f4*)b;

    for (long long gq = gq0; gq < NQ; gq += qstr) {
        const f4* __restrict__ pa = a4 + 36LL * gq;
        const f4* __restrict__ pb = b4 + 36LL * gq;

        f4 A[9], B[9];
        #pragma unroll
        for (int k = 0; k < 9; ++k) {
            A[k] = __builtin_nontemporal_load(pa + 4 * k + q);
            B[k] = __builtin_nontemporal_load(pb + 4 * k + q);
        }

        #pragma unroll
        for (int g = 0; g < 4; ++g) {
            float P0 = 0.0f, P1 = 0.0f, P2 = 0.0f, P3 = 0.0f;
            #pragma unroll
            for (int i = 0; i < 3; ++i) {
                const int k = 2 * g + i;
                const int r = 4 * k + q - 9 * g;   // local float4 idx, or OOR
                const f4 p = A[k] * B[k];
                const float lo1 = p.x;
                const float lo2 = lo1 + p.y;
                const float lo3 = lo2 + p.z;
                const float s   = lo3 + p.w;
                // window-local matrices: splits at r=2 (1|3), r=4 (2|2),
                // r=6 (3|1); r outside [0,8] matches nothing -> contributes 0
                P0 += (r == 0 || r == 1) ? s : (r == 2) ? lo1 : 0.0f;
                P1 += (r == 3) ? s : (r == 2) ? (s - lo1)
                                   : (r == 4) ? lo2 : 0.0f;
                P2 += (r == 5) ? s : (r == 4) ? (s - lo2)
                                   : (r == 6) ? lo3 : 0.0f;
                P3 += (r == 7 || r == 8) ? s : (r == 6) ? (s - lo3) : 0.0f;
            }
            // quad all-reduce (xor 1 + xor 2 stay within the aligned quad)
            P0 += __shfl_xor(P0, 1, 64); P0 += __shfl_xor(P0, 2, 64);
            P1 += __shfl_xor(P1, 1, 64); P1 += __shfl_xor(P1, 2, 64);
            P2 += __shfl_xor(P2, 1, 64); P2 += __shfl_xor(P2, 2, 64);
            P3 += __shfl_xor(P3, 1, 64); P3 += __shfl_xor(P3, 2, 64);

            const float d = (q == 0) ? P0 : (q == 1) ? P1
                          : (q == 2) ? P2 : P3;      // matrix 4g+q
            const float cv = fminf(1.0f, fmaxf(-1.0f, (d - 1.0f) * 0.5f));
            sum += acosf(cv);
        }
    }

    // tail matrices beyond 16*NQ (empty when M % 16 == 0)
    {
        const long long gid    = (long long)blockIdx.x * TPB + tid;
        const long long stride = (long long)gridDim.x * TPB;
        for (long long m = 16 * NQ + gid; m < M; m += stride) {
            float dd = 0.0f;
            #pragma unroll
            for (int j = 0; j < 9; ++j)
                dd = fmaf(a[m * 9 + j], b[m * 9 + j], dd);
            sum += acosf(fminf(1.0f, fmaxf(-1.0f, (dd - 1.0f) * 0.5f)));
        }
    }

    // wave shuffle reduce -> per-block LDS reduce
    #pragma unroll
    for (int off = 32; off > 0; off >>= 1)
        sum += __shfl_down(sum, off, 64);
    if ((tid & 63) == 0) wsum[tid >> 6] = sum;
    __syncthreads();
    if (tid == 0) {
        float s = 0.0f;
        #pragma unroll
        for (int i = 0; i < TPB / 64; ++i) s += wsum[i];
        if (use_atomic) atomicAdd(out, s * invM);   // fallback path
        else            ws[blockIdx.x] = s;          // no contention
    }
}

__global__ __launch_bounds__(256) void geo_finish(
    const float* __restrict__ ws, float* __restrict__ out,
    float invM, int nb)
{
    __shared__ float wsum[4];
    float s = 0.0f;
    for (int i = threadIdx.x; i < nb; i += 256) s += ws[i];
    #pragma unroll
    for (int off = 32; off > 0; off >>= 1)
        s += __shfl_down(s, off, 64);
    if ((threadIdx.x & 63) == 0) wsum[threadIdx.x >> 6] = s;
    __syncthreads();
    if (threadIdx.x == 0)
        out[0] = (wsum[0] + wsum[1] + wsum[2] + wsum[3]) * invM;
}

extern "C" void kernel_launch(void* const* d_in, const int* in_sizes, int n_in,
                              void* d_out, int out_size, void* d_ws, size_t ws_size,
                              hipStream_t stream) {
    const float* a = (const float*)d_in[0];
    const float* b = (const float*)d_in[1];
    float* out = (float*)d_out;

    const int n = in_sizes[0];   // flat float count = 9*M
    const int M = n / 9;         // number of 3x3 matrices

    const bool ws_ok = (ws_size >= (size_t)NBLOCKS * sizeof(float));
    if (!ws_ok) {
        // atomic fallback needs a zeroed accumulator (d_out is poisoned)
        hipMemsetAsync(out, 0, (size_t)out_size * sizeof(float), stream);
    }
    geo_partial<<<NBLOCKS, TPB, 0, stream>>>(
        a, b, (float*)d_ws, out, 1.0f / (float)M, M, ws_ok ? 0 : 1);
    if (ws_ok) {
        geo_finish<<<1, 256, 0, stream>>>(
            (const float*)d_ws, out, 1.0f / (float)M, NBLOCKS);
    }
}